// Round 2
// baseline (1384.158 us; speedup 1.0000x reference)
//
#include <hip/hip_runtime.h>
#include <hip/hip_bf16.h>
#include <stdint.h>
#include <math.h>

typedef __bf16 bf16_t;
typedef __bf16 bf16x8 __attribute__((ext_vector_type(8)));
typedef __bf16 bf16x4 __attribute__((ext_vector_type(4)));
typedef float floatx4 __attribute__((ext_vector_type(4)));

#define NN 8192   // nodes
#define DD 512    // model dim
#define FF 2048   // ffn dim
#define MM 4096   // masked nodes
#define KK 128    // genes per masked node

// ---------------------------------------------------------------------------
// async global->LDS 16B copy (dst must be wave-uniform base + lane*16 layout)
// ---------------------------------------------------------------------------
__device__ __forceinline__ void async_copy16(const void* g, void* l) {
    __builtin_amdgcn_global_load_lds(
        (const __attribute__((address_space(1))) void*)(uintptr_t)g,
        (__attribute__((address_space(3))) void*)(uint32_t)(uintptr_t)l,
        16, 0, 0);
}

// ---------------------------------------------------------------------------
// NT GEMM: C[M x Nc] = A[M x Kd] @ B[Nc x Kd]^T   (bf16 in, fp32 accum)
// EPI: 0=none, 1=scale, 2=+bias, 3=+bias+gelu(exact). OT = float or bf16.
// 128x128 tile, BK=32, 256 threads (4 waves 2x2), mfma_f32_16x16x32_bf16
// ---------------------------------------------------------------------------
template<int EPI, typename OT>
__global__ __launch_bounds__(256)
void gemm_nt(const bf16_t* __restrict__ A, const bf16_t* __restrict__ B,
             OT* __restrict__ C, int M, int Nc, int Kd,
             float scale, const float* __restrict__ bias)
{
    __shared__ bf16_t As[128 * 32];
    __shared__ bf16_t Bs[128 * 32];

    const int tid  = threadIdx.x;
    const int lane = tid & 63;
    const int wave = tid >> 6;
    const int wm   = (wave >> 1) << 6;
    const int wn   = (wave & 1) << 6;
    const int quad = lane >> 4;
    const int l16  = lane & 15;

    const long bm = (long)blockIdx.x * 128;
    const long bn = (long)blockIdx.y * 128;

    const int t0 = tid, t1 = tid + 256;
    const bf16_t* pA0 = A + (bm + (t0 >> 2)) * (long)Kd + (t0 & 3) * 8;
    const bf16_t* pA1 = A + (bm + (t1 >> 2)) * (long)Kd + (t1 & 3) * 8;
    const bf16_t* pB0 = B + (bn + (t0 >> 2)) * (long)Kd + (t0 & 3) * 8;
    const bf16_t* pB1 = B + (bn + (t1 >> 2)) * (long)Kd + (t1 & 3) * 8;
    bf16_t* lA0 = &As[t0 * 8];
    bf16_t* lA1 = &As[t1 * 8];
    bf16_t* lB0 = &Bs[t0 * 8];
    bf16_t* lB1 = &Bs[t1 * 8];

    floatx4 acc[4][4] = {};

    for (long k0 = 0; k0 < Kd; k0 += 32) {
        async_copy16(pA0 + k0, lA0);
        async_copy16(pA1 + k0, lA1);
        async_copy16(pB0 + k0, lB0);
        async_copy16(pB1 + k0, lB1);
        __syncthreads();

        bf16x8 af[4], bfr[4];
#pragma unroll
        for (int i = 0; i < 4; i++) {
            af[i]  = *(const bf16x8*)&As[(wm + i * 16 + l16) * 32 + quad * 8];
            bfr[i] = *(const bf16x8*)&Bs[(wn + i * 16 + l16) * 32 + quad * 8];
        }
#pragma unroll
        for (int mi = 0; mi < 4; mi++)
#pragma unroll
            for (int ni = 0; ni < 4; ni++)
                acc[mi][ni] = __builtin_amdgcn_mfma_f32_16x16x32_bf16(
                    af[mi], bfr[ni], acc[mi][ni], 0, 0, 0);
        __syncthreads();
    }

    // C/D layout: col = lane&15, row = quad*4 + reg (verified m89/m91)
#pragma unroll
    for (int mi = 0; mi < 4; mi++) {
        const long rbase = bm + wm + mi * 16 + quad * 4;
#pragma unroll
        for (int ni = 0; ni < 4; ni++) {
            const long col = bn + wn + ni * 16 + l16;
            float bv = (EPI >= 2) ? bias[col] : 0.0f;
#pragma unroll
            for (int r = 0; r < 4; r++) {
                float v = acc[mi][ni][r];
                if (EPI == 1) v *= scale;
                if (EPI >= 2) v += bv;
                if (EPI == 3) v = 0.5f * v * (1.0f + erff(v * 0.70710678118f));
                C[(rbase + r) * (long)Nc + col] = (OT)v;
            }
        }
    }
}

template<int EPI, typename OT>
static void launch_gemm(const bf16_t* A, const bf16_t* B, OT* C,
                        int M, int Nc, int Kd, float scale, const float* bias,
                        hipStream_t s)
{
    dim3 g(M / 128, Nc / 128);
    gemm_nt<EPI, OT><<<g, 256, 0, s>>>(A, B, C, M, Nc, Kd, scale, bias);
}

// ---------------------------------------------------------------------------
// transpose + f32->bf16 convert: in[R x C] f32 -> out[C x R] bf16
// ---------------------------------------------------------------------------
__global__ __launch_bounds__(256)
void transpose_f2b(const float* __restrict__ in, bf16_t* __restrict__ out,
                   int R, int C)
{
    __shared__ float tile[32][33];
    const int bx = blockIdx.x * 32;  // col base in 'in'
    const int by = blockIdx.y * 32;  // row base in 'in'
    const int tx = threadIdx.x, ty = threadIdx.y;  // (32, 8)
#pragma unroll
    for (int i = 0; i < 32; i += 8)
        tile[ty + i][tx] = in[(long)(by + ty + i) * C + bx + tx];
    __syncthreads();
#pragma unroll
    for (int i = 0; i < 32; i += 8)
        out[(long)(bx + ty + i) * R + by + tx] = (bf16_t)tile[tx][ty + i];
}

// ---------------------------------------------------------------------------
// row softmax over rows of length 8192: bf16 in-place, optional f32 copy out
// ---------------------------------------------------------------------------
template<bool WF>
__global__ __launch_bounds__(256)
void softmax_rows(bf16_t* __restrict__ S, float* __restrict__ F)
{
    const long row = blockIdx.x;
    bf16_t* p = S + row * (long)NN;
    const int tid = threadIdx.x;
    const int wave = tid >> 6;

    bf16x8 v[4];
    float lmax = -3.0e38f;
#pragma unroll
    for (int i = 0; i < 4; i++) {
        v[i] = *(const bf16x8*)(p + (tid + i * 256) * 8);
#pragma unroll
        for (int j = 0; j < 8; j++) lmax = fmaxf(lmax, (float)v[i][j]);
    }
#pragma unroll
    for (int off = 32; off > 0; off >>= 1) lmax = fmaxf(lmax, __shfl_xor(lmax, off));

    __shared__ float red[4];
    if ((tid & 63) == 0) red[wave] = lmax;
    __syncthreads();
    const float gmax = fmaxf(fmaxf(red[0], red[1]), fmaxf(red[2], red[3]));
    __syncthreads();

    float e[4][8];
    float lsum = 0.0f;
#pragma unroll
    for (int i = 0; i < 4; i++)
#pragma unroll
        for (int j = 0; j < 8; j++) {
            e[i][j] = expf((float)v[i][j] - gmax);
            lsum += e[i][j];
        }
#pragma unroll
    for (int off = 32; off > 0; off >>= 1) lsum += __shfl_xor(lsum, off);
    if ((tid & 63) == 0) red[wave] = lsum;
    __syncthreads();
    const float inv = 1.0f / (red[0] + red[1] + red[2] + red[3]);

#pragma unroll
    for (int i = 0; i < 4; i++) {
        bf16x8 o;
        float w[8];
#pragma unroll
        for (int j = 0; j < 8; j++) {
            w[j] = e[i][j] * inv;
            o[j] = (bf16_t)w[j];
        }
        *(bf16x8*)(p + (tid + i * 256) * 8) = o;
        if (WF) {
            float* q = F + row * (long)NN + (tid + i * 256) * 8;
#pragma unroll
            for (int j = 0; j < 8; j++) q[j] = w[j];
        }
    }
}

// ---------------------------------------------------------------------------
// LayerNorm(a + b) * g + be ; a,b f32; emits bf16 (ob) and f32 (of)
// one wave per row of DD=512
// ---------------------------------------------------------------------------
__global__ __launch_bounds__(64)
void add_ln(const float* __restrict__ a, const float* __restrict__ b,
            const float* __restrict__ g, const float* __restrict__ be,
            bf16_t* __restrict__ ob, float* __restrict__ of)
{
    const long row = blockIdx.x;
    const int lane = threadIdx.x;
    const long base = row * DD + lane * 8;
    float v[8], s = 0.0f, s2 = 0.0f;
#pragma unroll
    for (int j = 0; j < 8; j++) {
        v[j] = a[base + j] + b[base + j];
        s += v[j]; s2 += v[j] * v[j];
    }
#pragma unroll
    for (int off = 32; off > 0; off >>= 1) {
        s  += __shfl_xor(s,  off);
        s2 += __shfl_xor(s2, off);
    }
    const float mu  = s * (1.0f / DD);
    const float var = s2 * (1.0f / DD) - mu * mu;
    const float inv = rsqrtf(var + 1e-5f);
    bf16x8 o;
#pragma unroll
    for (int j = 0; j < 8; j++) {
        float r = (v[j] - mu) * inv * g[lane * 8 + j] + be[lane * 8 + j];
        o[j] = (bf16_t)r;
        of[base + j] = r;
    }
    *(bf16x8*)(ob + base) = o;
}

// ---------------------------------------------------------------------------
// use_x construction, masked scatter/gather (f32 I/O, int32 indices)
// ---------------------------------------------------------------------------
__global__ __launch_bounds__(256)
void build_usex(const float* __restrict__ x, bf16_t* __restrict__ ub,
                float* __restrict__ uf)
{
    const long i = ((long)blockIdx.x * 256 + threadIdx.x) * 4;
    const float4 v = *(const float4*)(x + i);
    *(float4*)(uf + i) = v;
    bf16x4 o = { (bf16_t)v.x, (bf16_t)v.y, (bf16_t)v.z, (bf16_t)v.w };
    *(bf16x4*)(ub + i) = o;
}

__global__ __launch_bounds__(256)
void scatter_zero(bf16_t* __restrict__ ub, float* __restrict__ uf,
                  const int* __restrict__ mn, const int* __restrict__ gi)
{
    const int i = blockIdx.x * 256 + threadIdx.x;   // grid = MM*KK/256
    const long idx = (long)mn[i >> 7] * DD + gi[i];
    ub[idx] = (bf16_t)0.0f;
    uf[idx] = 0.0f;
}

__global__ __launch_bounds__(256)
void gather_mk(const float* __restrict__ src, const int* __restrict__ mn,
               const int* __restrict__ gi, float* __restrict__ dst)
{
    const int i = blockIdx.x * 256 + threadIdx.x;
    dst[i] = src[(long)mn[i >> 7] * DD + gi[i]];
}

// ---------------------------------------------------------------------------
extern "C" void kernel_launch(void* const* d_in, const int* in_sizes, int n_in,
                              void* d_out, int out_size, void* d_ws, size_t ws_size,
                              hipStream_t stream)
{
    const float* x      = (const float*)d_in[0];
    const int*   mn     = (const int*)d_in[1];
    const int*   gi     = (const int*)d_in[2];
    const float* Wq_e   = (const float*)d_in[3];
    const float* Wk_e   = (const float*)d_in[4];
    const float* Wv_e   = (const float*)d_in[5];
    const float* ln1_g  = (const float*)d_in[6];
    const float* ln1_b  = (const float*)d_in[7];
    const float* ff_W1  = (const float*)d_in[8];
    const float* ff_b1  = (const float*)d_in[9];
    const float* ff_W2  = (const float*)d_in[10];
    const float* ff_b2  = (const float*)d_in[11];
    const float* ln2_g  = (const float*)d_in[12];
    const float* ln2_b  = (const float*)d_in[13];
    const float* Wq_d   = (const float*)d_in[14];
    const float* Wk_d   = (const float*)d_in[15];
    const float* Wv_d   = (const float*)d_in[16];
    const float* ln3_g  = (const float*)d_in[17];
    const float* ln3_b  = (const float*)d_in[18];
    const float* ln4_g  = (const float*)d_in[19];
    const float* ln4_b  = (const float*)d_in[20];
    const float* head_W = (const float*)d_in[21];
    const float* head_b = (const float*)d_in[22];

    float* outf     = (float*)d_out;
    float* o_xinit  = outf;                           // [MM*KK]
    float* o_xrecon = outf + (size_t)MM * KK;         // [MM*KK]
    float* o_encw   = outf + (size_t)2 * MM * KK;     // [NN*NN]
    float* o_recon  = o_encw + (size_t)NN * NN;       // [NN*DD]

    // workspace carve-up (256B aligned) with lifetime aliasing
    char* ws = (char*)d_ws;
    size_t off = 0;
    auto alloc = [&](size_t bytes) -> void* {
        void* p = ws + off;
        off += (bytes + 255) & ~(size_t)255;
        return p;
    };
    const size_t NDb = (size_t)NN * DD * sizeof(bf16_t);   // 8 MiB
    const size_t NDf = (size_t)NN * DD * sizeof(float);    // 16 MiB

    bf16_t* usex_b = (bf16_t*)alloc(NDb);
    bf16_t* q_b    = (bf16_t*)alloc(NDb);
    bf16_t* k_b    = (bf16_t*)alloc(NDb);
    bf16_t* vt_b   = (bf16_t*)alloc(NDb);
    bf16_t* hid_b  = (bf16_t*)alloc(NDb);
    float*  usex_f = (float*)alloc(NDf);
    float*  resA_f = (float*)alloc(NDf);
    float*  gout_f = (float*)alloc(NDf);
    bf16_t* wt_qe  = (bf16_t*)alloc((size_t)DD * DD * 2);
    bf16_t* wt_ke  = (bf16_t*)alloc((size_t)DD * DD * 2);
    bf16_t* wt_ve  = (bf16_t*)alloc((size_t)DD * DD * 2);
    bf16_t* wt_qd  = (bf16_t*)alloc((size_t)DD * DD * 2);
    bf16_t* wt_kd  = (bf16_t*)alloc((size_t)DD * DD * 2);
    bf16_t* wt_vd  = (bf16_t*)alloc((size_t)DD * DD * 2);
    bf16_t* wt_h   = (bf16_t*)alloc((size_t)DD * DD * 2);
    bf16_t* w1t    = (bf16_t*)alloc((size_t)DD * FF * 2);
    bf16_t* w2t    = (bf16_t*)alloc((size_t)FF * DD * 2);
    bf16_t* scores = (bf16_t*)alloc((size_t)NN * NN * 2);  // 128 MiB
    // aliases (disjoint lifetimes):
    bf16_t* t1_b   = scores;           // [NN*FF] bf16, FFN mid — attn phases done
    float*  resB_f = usex_f;           // usex_f dead after ln1; resB born at ln2
    (void)ws_size; (void)in_sizes; (void)n_in; (void)out_size;

    auto tr = [&](const float* in, bf16_t* o, int R, int C) {
        transpose_f2b<<<dim3(C / 32, R / 32), dim3(32, 8), 0, stream>>>(in, o, R, C);
    };
    const float SC = 0.04419417382f;  // 1/sqrt(512)

    // 0. weights -> transposed bf16
    tr(Wq_e, wt_qe, DD, DD);  tr(Wk_e, wt_ke, DD, DD);  tr(Wv_e, wt_ve, DD, DD);
    tr(Wq_d, wt_qd, DD, DD);  tr(Wk_d, wt_kd, DD, DD);  tr(Wv_d, wt_vd, DD, DD);
    tr(head_W, wt_h, DD, DD); tr(ff_W1, w1t, DD, FF);   tr(ff_W2, w2t, FF, DD);

    // 1. use_x (bf16 + f32) with masked zeros; x_init gather (exact f32)
    build_usex<<<NN * DD / 1024, 256, 0, stream>>>(x, usex_b, usex_f);
    scatter_zero<<<MM * KK / 256, 256, 0, stream>>>(usex_b, usex_f, mn, gi);
    gather_mk<<<MM * KK / 256, 256, 0, stream>>>(x, mn, gi, o_xinit);

    // 2. encoder attention
    launch_gemm<0>(usex_b, wt_qe, q_b,   NN, DD, DD, 0.f, nullptr, stream);
    launch_gemm<0>(usex_b, wt_ke, k_b,   NN, DD, DD, 0.f, nullptr, stream);
    launch_gemm<0>(usex_b, wt_ve, gout_f, NN, DD, DD, 0.f, nullptr, stream);
    tr(gout_f, vt_b, NN, DD);                               // V^T bf16 [DD x NN]
    launch_gemm<1>(q_b, k_b, scores, NN, NN, DD, SC, nullptr, stream);
    softmax_rows<true><<<NN, 256, 0, stream>>>(scores, o_encw);  // bf16 + f32 out
    launch_gemm<0>(scores, vt_b, gout_f, NN, DD, NN, 0.f, nullptr, stream);
    add_ln<<<NN, 64, 0, stream>>>(gout_f, usex_f, ln1_g, ln1_b, hid_b, resA_f);

    // 3. encoder FFN (scores dead -> t1 alias live)
    launch_gemm<3>(hid_b, w1t, t1_b, NN, FF, DD, 0.f, ff_b1, stream);
    launch_gemm<2>(t1_b, w2t, gout_f, NN, DD, FF, 0.f, ff_b2, stream);
    add_ln<<<NN, 64, 0, stream>>>(gout_f, resA_f, ln2_g, ln2_b, hid_b, resB_f);

    // 4. decoder attention (t1 dead -> scores alias live)
    launch_gemm<0>(hid_b, wt_qd, q_b,   NN, DD, DD, 0.f, nullptr, stream);
    launch_gemm<0>(hid_b, wt_kd, k_b,   NN, DD, DD, 0.f, nullptr, stream);
    launch_gemm<0>(hid_b, wt_vd, gout_f, NN, DD, DD, 0.f, nullptr, stream);
    tr(gout_f, vt_b, NN, DD);
    launch_gemm<1>(q_b, k_b, scores, NN, NN, DD, SC, nullptr, stream);
    softmax_rows<false><<<NN, 256, 0, stream>>>(scores, nullptr);
    launch_gemm<0>(scores, vt_b, gout_f, NN, DD, NN, 0.f, nullptr, stream);
    add_ln<<<NN, 64, 0, stream>>>(gout_f, resB_f, ln3_g, ln3_b, hid_b, resA_f);

    // 5. decoder FFN (scores dead -> t1 alias live)
    launch_gemm<3>(hid_b, w1t, t1_b, NN, FF, DD, 0.f, ff_b1, stream);
    launch_gemm<2>(t1_b, w2t, gout_f, NN, DD, FF, 0.f, ff_b2, stream);
    add_ln<<<NN, 64, 0, stream>>>(gout_f, resA_f, ln4_g, ln4_b, hid_b, o_recon);

    // 6. head + masked gather
    launch_gemm<2>(hid_b, wt_h, gout_f, NN, DD, DD, 0.f, head_b, stream);
    gather_mk<<<MM * KK / 256, 256, 0, stream>>>(gout_f, mn, gi, o_xrecon);
}